// Round 9
// baseline (574.489 us; speedup 1.0000x reference)
//
#include <hip/hip_runtime.h>

#define EMB 64
#define B2SHIFT 8                 // 256 dst rows per bucket
#define B2ROWS 256
#define MAXB 1024                 // LDS hist capacity (586 buckets actual)

typedef short v8s __attribute__((ext_vector_type(8)));
typedef float v4f __attribute__((ext_vector_type(4)));

__device__ __forceinline__ float b2f(unsigned short u) {
    return __uint_as_float(((unsigned int)u) << 16);
}
__device__ __forceinline__ float b2f_lo(unsigned int u) {
    return __uint_as_float(u << 16);
}
__device__ __forceinline__ float b2f_hi(unsigned int u) {
    return __uint_as_float(u & 0xFFFF0000u);
}
__device__ __forceinline__ unsigned short f2b(float f) {
    unsigned int u = __float_as_uint(f);
    u += 0x7FFF + ((u >> 16) & 1);          // round-to-nearest-even
    return (unsigned short)(u >> 16);
}

// ---------------------------------------------------------------------------
// init (x4 vectorized): fills ping-pong buffer 0 + all_eb[:,0:64]
// ---------------------------------------------------------------------------
__global__ void k_init_ego(const float* __restrict__ user_emb,
                           const float* __restrict__ item_emb,
                           const float* __restrict__ dsq,
                           unsigned short* __restrict__ egob,
                           unsigned short* __restrict__ egow,
                           unsigned short* __restrict__ all_eb,
                           int n_user, int N) {
    int idx = blockIdx.x * blockDim.x + threadIdx.x;   // over N*16
    int total = N * 16;
    if (idx >= total) return;
    int n = idx >> 4;
    int q = idx & 15;                                  // comps 4q..4q+3
    float4 v = (n < n_user)
        ? ((const float4*)user_emb)[idx]
        : ((const float4*)item_emb)[(size_t)(n - n_user) * 16 + q];
    float dn = dsq[n];
    unsigned int pb0 = (unsigned)f2b(v.x) | ((unsigned)f2b(v.y) << 16);
    unsigned int pb1 = (unsigned)f2b(v.z) | ((unsigned)f2b(v.w) << 16);
    unsigned int pw0 = (unsigned)f2b(dn * v.x) | ((unsigned)f2b(dn * v.y) << 16);
    unsigned int pw1 = (unsigned)f2b(dn * v.z) | ((unsigned)f2b(dn * v.w) << 16);
    unsigned int* egobd = (unsigned int*)egob;
    unsigned int* egowd = (unsigned int*)egow;
    egobd[idx * 2 + 0] = pb0;
    egobd[idx * 2 + 1] = pb1;
    egowd[idx * 2 + 0] = pw0;
    egowd[idx * 2 + 1] = pw1;
    unsigned int* ae = (unsigned int*)all_eb;
    __builtin_nontemporal_store(pb0, &ae[(size_t)n * 128 + q * 2 + 0]);
    __builtin_nontemporal_store(pb1, &ae[(size_t)n * 128 + q * 2 + 1]);
}

// ---------------------------------------------------------------------------
// Bucket histogram (586 buckets): LDS pre-aggregation, ~300K global atomics
// ---------------------------------------------------------------------------
__global__ __launch_bounds__(256) void k_bhist(const int* __restrict__ dst,
                                               int* __restrict__ bins,
                                               int M, int nb2) {
    __shared__ int h[MAXB];
    for (int i = threadIdx.x; i < nb2; i += 256) h[i] = 0;
    __syncthreads();
    for (int e = blockIdx.x * 256 + threadIdx.x; e < M; e += gridDim.x * 256)
        atomicAdd(&h[dst[e] >> B2SHIFT], 1);
    __syncthreads();
    for (int i = threadIdx.x; i < nb2; i += 256)
        if (h[i]) atomicAdd(&bins[i], h[i]);
}

// ---------------------------------------------------------------------------
// Exclusive scan of nb2 (<=1024) bins -> boff[0..P], bcur copy; row_ptr[N]=M
// ---------------------------------------------------------------------------
__global__ __launch_bounds__(1024) void k_bscan(const int* __restrict__ bins,
                                                int* __restrict__ boff,
                                                int* __restrict__ bcur,
                                                int* __restrict__ row_ptr,
                                                int P, int N) {
    __shared__ int buf[1024];
    int tid = threadIdx.x;
    int v = (tid < P) ? bins[tid] : 0;
    buf[tid] = v;
    __syncthreads();
    for (int d = 1; d < 1024; d <<= 1) {
        int add = (tid >= d) ? buf[tid - d] : 0;
        __syncthreads();
        buf[tid] += add;
        __syncthreads();
    }
    if (tid < P) {
        int excl = buf[tid] - v;
        boff[tid] = excl;
        bcur[tid] = excl;
    }
    if (tid == P - 1) {
        boff[P] = buf[tid];
        row_ptr[N] = buf[tid];
    }
}

// ---------------------------------------------------------------------------
// Multisplit pass 1: block-private runs per bucket (single-writer lines)
// entry = (src << 8) | (dst & 255)
// ---------------------------------------------------------------------------
__global__ __launch_bounds__(256) void k_bin(const int* __restrict__ src,
                                             const int* __restrict__ dst,
                                             int* __restrict__ bcur,
                                             int* __restrict__ binned,
                                             int M, int nb2) {
    __shared__ int hist[MAXB];
    __shared__ int runcur[MAXB];
    int chunk = (M + gridDim.x - 1) / gridDim.x;
    int lo = blockIdx.x * chunk;
    int hi = min(lo + chunk, M);
    for (int i = threadIdx.x; i < nb2; i += 256) hist[i] = 0;
    __syncthreads();
    for (int e = lo + threadIdx.x; e < hi; e += 256)
        atomicAdd(&hist[dst[e] >> B2SHIFT], 1);
    __syncthreads();
    for (int i = threadIdx.x; i < nb2; i += 256) {
        int c = hist[i];
        runcur[i] = c ? atomicAdd(&bcur[i], c) : 0;
    }
    __syncthreads();
    for (int e = lo + threadIdx.x; e < hi; e += 256) {
        int d = dst[e];
        int pos = atomicAdd(&runcur[d >> B2SHIFT], 1);
        binned[pos] = (src[e] << B2SHIFT) | (d & (B2ROWS - 1));
    }
}

// ---------------------------------------------------------------------------
// Multisplit pass 2 + CSR finalize: per-bucket LDS histogram -> scan ->
// row_ptr & dsq -> scatter csr in the bucket's L2-local window
// ---------------------------------------------------------------------------
__global__ __launch_bounds__(256) void k_csrb(const int* __restrict__ boff,
                                              const int* __restrict__ binned,
                                              int* __restrict__ row_ptr,
                                              float* __restrict__ dsq,
                                              int* __restrict__ csr, int N) {
    __shared__ int hist[B2ROWS];
    __shared__ int scan[B2ROWS];
    int b = blockIdx.x;
    int beg = boff[b], end = boff[b + 1];
    int tid = threadIdx.x;
    hist[tid] = 0;
    __syncthreads();
    for (int e = beg + tid; e < end; e += 256)
        atomicAdd(&hist[binned[e] & (B2ROWS - 1)], 1);
    __syncthreads();
    int c = hist[tid];
    scan[tid] = c;
    __syncthreads();
    for (int d = 1; d < B2ROWS; d <<= 1) {
        int add = (tid >= d) ? scan[tid - d] : 0;
        __syncthreads();
        scan[tid] += add;
        __syncthreads();
    }
    int excl = beg + scan[tid] - c;
    int node = (b << B2SHIFT) + tid;
    if (node < N) {
        row_ptr[node] = excl;
        dsq[node] = (c > 0) ? rsqrtf((float)c) : 0.0f;
    }
    __syncthreads();
    hist[tid] = excl;               // reuse as per-node cursor
    __syncthreads();
    for (int e = beg + tid; e < end; e += 256) {
        int v = binned[e];
        int pos = atomicAdd(&hist[v & (B2ROWS - 1)], 1);
        csr[pos] = v >> B2SHIFT;
    }
}

// ---------------------------------------------------------------------------
// v4 gather body for ONE node (proven: scalar-pipe indices, named scalars)
// ---------------------------------------------------------------------------
__device__ __forceinline__ float gather_node(const int* __restrict__ csr,
                                             const unsigned short* __restrict__ egow,
                                             int beg, int end, int lane) {
    float a0 = 0.f, a1 = 0.f, a2 = 0.f, a3 = 0.f;
    int e = beg;
    for (; e + 16 <= end; e += 16) {
        int s0  = csr[e + 0],  s1  = csr[e + 1],  s2  = csr[e + 2],  s3  = csr[e + 3];
        int s4  = csr[e + 4],  s5  = csr[e + 5],  s6  = csr[e + 6],  s7  = csr[e + 7];
        int s8  = csr[e + 8],  s9  = csr[e + 9],  s10 = csr[e + 10], s11 = csr[e + 11];
        int s12 = csr[e + 12], s13 = csr[e + 13], s14 = csr[e + 14], s15 = csr[e + 15];
        float v0  = b2f(egow[(size_t)s0  * EMB + lane]);
        float v1  = b2f(egow[(size_t)s1  * EMB + lane]);
        float v2  = b2f(egow[(size_t)s2  * EMB + lane]);
        float v3  = b2f(egow[(size_t)s3  * EMB + lane]);
        float v4  = b2f(egow[(size_t)s4  * EMB + lane]);
        float v5  = b2f(egow[(size_t)s5  * EMB + lane]);
        float v6  = b2f(egow[(size_t)s6  * EMB + lane]);
        float v7  = b2f(egow[(size_t)s7  * EMB + lane]);
        float v8  = b2f(egow[(size_t)s8  * EMB + lane]);
        float v9  = b2f(egow[(size_t)s9  * EMB + lane]);
        float v10 = b2f(egow[(size_t)s10 * EMB + lane]);
        float v11 = b2f(egow[(size_t)s11 * EMB + lane]);
        float v12 = b2f(egow[(size_t)s12 * EMB + lane]);
        float v13 = b2f(egow[(size_t)s13 * EMB + lane]);
        float v14 = b2f(egow[(size_t)s14 * EMB + lane]);
        float v15 = b2f(egow[(size_t)s15 * EMB + lane]);
        a0 += v0;  a1 += v1;  a2 += v2;  a3 += v3;
        a0 += v4;  a1 += v5;  a2 += v6;  a3 += v7;
        a0 += v8;  a1 += v9;  a2 += v10; a3 += v11;
        a0 += v12; a1 += v13; a2 += v14; a3 += v15;
    }
    for (; e + 4 <= end; e += 4) {
        int s0 = csr[e + 0], s1 = csr[e + 1], s2 = csr[e + 2], s3 = csr[e + 3];
        float v0 = b2f(egow[(size_t)s0 * EMB + lane]);
        float v1 = b2f(egow[(size_t)s1 * EMB + lane]);
        float v2 = b2f(egow[(size_t)s2 * EMB + lane]);
        float v3 = b2f(egow[(size_t)s3 * EMB + lane]);
        a0 += v0; a1 += v1; a2 += v2; a3 += v3;
    }
    for (; e < end; ++e) {
        int s0 = csr[e];
        a0 += b2f(egow[(size_t)s0 * EMB + lane]);
    }
    return (a0 + a1) + (a2 + a3);
}

// ---------------------------------------------------------------------------
// FUSED layer kernel: block = 16 nodes = one MFMA row-tile. Phase 1: wave w
// gathers nodes base+4w..+3 (v4 body), X rows -> LDS sX[16][136] (never hits
// global). Phase 2 (1 barrier): wave w computes nt=w quarter of the r8
// transposed MFMA (4 mfma), row-norm via in-lane ssq + shfl(16,32) +
// cross-wave sS reduce. PING-PONG ego buffers (in/out) prevent the fused
// read/write race on egob/egow across blocks.
// ---------------------------------------------------------------------------
__global__ __launch_bounds__(256, 2) void k_fused(
        const int* __restrict__ row_ptr, const int* __restrict__ csr,
        const float* __restrict__ dsq,
        const unsigned short* __restrict__ egob_in,
        const unsigned short* __restrict__ egow_in,
        unsigned short* __restrict__ egob_out,
        unsigned short* __restrict__ egow_out,
        const float* __restrict__ Wgc, const float* __restrict__ bgc,
        const float* __restrict__ Wbi, const float* __restrict__ bbi,
        unsigned short* __restrict__ all_eb, int N, int layer_col,
        int write_next) {
    __shared__ unsigned short sWT[64 * 136];          // [out_col][k]
    __shared__ __align__(16) unsigned short sX[16 * 136];  // [row][k]
    __shared__ __align__(16) float sB[64];
    __shared__ float sS[4][16];
    int tid = threadIdx.x;
    int wave = tid >> 6, lane = tid & 63;

    // stage W^T (bf16) + fused bias; no barrier yet (covered by the one below)
    for (int i = tid; i < 64 * 64; i += 256) {
        int k = i >> 6, n = i & 63;
        sWT[n * 136 + k]      = f2b(Wgc[i]);
        sWT[n * 136 + 64 + k] = f2b(Wbi[i]);
    }
    if (tid < 64) sB[tid] = bgc[tid] + bbi[tid];

    // ---- phase 1: gather 4 nodes per wave into sX ----
    int base_n = (blockIdx.x << 4) + wave * 4;
#pragma unroll
    for (int j = 0; j < 4; ++j) {
        int n = base_n + j;
        int r = wave * 4 + j;
        if (n < N) {
            int beg = __builtin_amdgcn_readfirstlane(row_ptr[n]);
            int end = __builtin_amdgcn_readfirstlane(row_ptr[n + 1]);
            float sum = gather_node(csr, egow_in, beg, end, lane);
            float s = dsq[n] * sum;
            float eg = b2f(egob_in[(size_t)n * EMB + lane]);
            sX[r * 136 + lane] = f2b(s);
            sX[r * 136 + 64 + lane] = f2b(s * eg);
        } else {
            sX[r * 136 + lane] = 0;
            sX[r * 136 + 64 + lane] = 0;
        }
    }
    __syncthreads();

    // ---- phase 2: wave w = nt quarter of transposed MFMA ----
    int q = lane >> 4, col = lane & 15;
    v8s Bf0 = *(const v8s*)&sWT[(wave * 16 + col) * 136 + 0 * 32 + q * 8];
    v8s Bf1 = *(const v8s*)&sWT[(wave * 16 + col) * 136 + 1 * 32 + q * 8];
    v8s Bf2 = *(const v8s*)&sWT[(wave * 16 + col) * 136 + 2 * 32 + q * 8];
    v8s Bf3 = *(const v8s*)&sWT[(wave * 16 + col) * 136 + 3 * 32 + q * 8];
    v8s Af0 = *(const v8s*)&sX[col * 136 + 0 * 32 + q * 8];
    v8s Af1 = *(const v8s*)&sX[col * 136 + 1 * 32 + q * 8];
    v8s Af2 = *(const v8s*)&sX[col * 136 + 2 * 32 + q * 8];
    v8s Af3 = *(const v8s*)&sX[col * 136 + 3 * 32 + q * 8];
    float4 bias4 = ((const float4*)sB)[wave * 4 + q];
    v4f acc = (v4f){bias4.x, bias4.y, bias4.z, bias4.w};
    acc = __builtin_amdgcn_mfma_f32_16x16x32_bf16(Bf0, Af0, acc, 0, 0, 0);
    acc = __builtin_amdgcn_mfma_f32_16x16x32_bf16(Bf1, Af1, acc, 0, 0, 0);
    acc = __builtin_amdgcn_mfma_f32_16x16x32_bf16(Bf2, Af2, acc, 0, 0, 0);
    acc = __builtin_amdgcn_mfma_f32_16x16x32_bf16(Bf3, Af3, acc, 0, 0, 0);

    // epilogue: leaky-relu, ssq over this wave's 4 cols, shfl over q,
    // cross-wave reduce for the full 64-col row norm
    float vv0 = acc[0] > 0.f ? acc[0] : 0.2f * acc[0];
    float vv1 = acc[1] > 0.f ? acc[1] : 0.2f * acc[1];
    float vv2 = acc[2] > 0.f ? acc[2] : 0.2f * acc[2];
    float vv3 = acc[3] > 0.f ? acc[3] : 0.2f * acc[3];
    float ssq = vv0 * vv0 + vv1 * vv1 + vv2 * vv2 + vv3 * vv3;
    ssq += __shfl_xor(ssq, 16, 64);
    ssq += __shfl_xor(ssq, 32, 64);
    if (lane < 16) sS[wave][lane] = ssq;       // lanes 0-15: q=0, col=lane
    __syncthreads();
    float tot = sS[0][col] + sS[1][col] + sS[2][col] + sS[3][col];
    float inv = 1.0f / fmaxf(sqrtf(tot), 1e-12f);

    int row = (blockIdx.x << 4) + col;
    if (row < N) {
        unsigned int* ae = (unsigned int*)all_eb;
        size_t aeBase = (size_t)row * 128 + (layer_col >> 1);
        int cd = (wave * 16 + q * 4) >> 1;
        unsigned int p0 = (unsigned)f2b(vv0 * inv) | ((unsigned)f2b(vv1 * inv) << 16);
        unsigned int p1 = (unsigned)f2b(vv2 * inv) | ((unsigned)f2b(vv3 * inv) << 16);
        __builtin_nontemporal_store(p0, &ae[aeBase + cd + 0]);
        __builtin_nontemporal_store(p1, &ae[aeBase + cd + 1]);
        if (write_next) {
            float dn = dsq[row];
            unsigned int* eb = (unsigned int*)egob_out;
            unsigned int* ew = (unsigned int*)egow_out;
            size_t base = (size_t)row * 32;
            unsigned int b0 = (unsigned)f2b(vv0) | ((unsigned)f2b(vv1) << 16);
            unsigned int b1 = (unsigned)f2b(vv2) | ((unsigned)f2b(vv3) << 16);
            eb[base + cd + 0] = b0;
            eb[base + cd + 1] = b1;
            unsigned int w0 = (unsigned)f2b(vv0 * dn) | ((unsigned)f2b(vv1 * dn) << 16);
            unsigned int w1 = (unsigned)f2b(vv2 * dn) | ((unsigned)f2b(vv3 * dn) << 16);
            ew[base + cd + 0] = w0;
            ew[base + cd + 1] = w1;
        }
    }
}

// ---------------------------------------------------------------------------
// gather (x4 vectorized): thread per 4 comps, 2 dwords in -> float4 out
// ---------------------------------------------------------------------------
__global__ void k_gather(const unsigned short* __restrict__ all_eb,
                         const int* __restrict__ users,
                         const int* __restrict__ pos,
                         const int* __restrict__ neg,
                         float* __restrict__ out, int n_user, int batch) {
    int idx = blockIdx.x * blockDim.x + threadIdx.x;
    int total = batch * 64;
    if (idx >= 3 * total) return;
    int which = idx / total;
    int r = idx - which * total;
    int b = r >> 6;
    int q = r & 63;                       // 4-comp group within the 256-row
    int node;
    if (which == 0) node = users[b];
    else if (which == 1) node = n_user + pos[b];
    else node = n_user + neg[b];
    const unsigned int* ae = (const unsigned int*)all_eb;
    unsigned int d0 = ae[(size_t)node * 128 + q * 2 + 0];
    unsigned int d1 = ae[(size_t)node * 128 + q * 2 + 1];
    float4 o;
    o.x = b2f_lo(d0);
    o.y = b2f_hi(d0);
    o.z = b2f_lo(d1);
    o.w = b2f_hi(d1);
    ((float4*)out)[idx] = o;
}

static inline size_t align256(size_t x) { return (x + 255) & ~(size_t)255; }

extern "C" void kernel_launch(void* const* d_in, const int* in_sizes, int n_in,
                              void* d_out, int out_size, void* d_ws, size_t ws_size,
                              hipStream_t stream) {
    const float* user_emb = (const float*)d_in[0];
    const float* item_emb = (const float*)d_in[1];
    const float* W_gc = (const float*)d_in[2];
    const float* b_gc = (const float*)d_in[3];
    const float* W_bi = (const float*)d_in[4];
    const float* b_bi = (const float*)d_in[5];
    const int* edge_src = (const int*)d_in[7];
    const int* edge_dst = (const int*)d_in[8];
    const int* users = (const int*)d_in[9];
    const int* pos = (const int*)d_in[10];
    const int* neg = (const int*)d_in[11];

    int n_user = in_sizes[0] / EMB;
    int n_item = in_sizes[1] / EMB;
    int N = n_user + n_item;
    int M = in_sizes[6];
    int layers = in_sizes[2] / (EMB * EMB);
    int batch = in_sizes[9];
    float* out = (float*)d_out;

    int nb2 = (N + B2ROWS - 1) >> B2SHIFT;       // 586 buckets
    int nrt = (N + 15) >> 4;                     // 16-row tiles

    // workspace carve (~187 MB; X dropped, ego ping-pong added)
    char* p = (char*)d_ws;
    unsigned short* egob0 = (unsigned short*)p;  p += align256((size_t)N * EMB * 2);
    unsigned short* egow0 = (unsigned short*)p;  p += align256((size_t)N * EMB * 2);
    unsigned short* egob1 = (unsigned short*)p;  p += align256((size_t)N * EMB * 2);
    unsigned short* egow1 = (unsigned short*)p;  p += align256((size_t)N * EMB * 2);
    unsigned short* all_eb = (unsigned short*)p; p += align256((size_t)N * 256 * 2);
    float* dsq = (float*)p;            p += align256((size_t)N * 4);
    int* row_ptr = (int*)p;            p += align256((size_t)(N + 1) * 4);
    int* bins = (int*)p;               p += align256((size_t)nb2 * 4);
    int* boff = (int*)p;               p += align256((size_t)(nb2 + 1) * 4);
    int* bcur = (int*)p;               p += align256((size_t)nb2 * 4);
    int* binned = (int*)p;             p += align256((size_t)M * 4);
    int* csr = (int*)p;                p += align256((size_t)M * 4);

    hipMemsetAsync(bins, 0, (size_t)nb2 * 4, stream);   // 2.3 KB

    // bucket-first CSR build (produces row_ptr, dsq, csr)
    k_bhist<<<512, 256, 0, stream>>>(edge_dst, bins, M, nb2);
    k_bscan<<<1, 1024, 0, stream>>>(bins, boff, bcur, row_ptr, nb2, N);
    k_bin<<<512, 256, 0, stream>>>(edge_src, edge_dst, bcur, binned, M, nb2);
    k_csrb<<<nb2, 256, 0, stream>>>(boff, binned, row_ptr, dsq, csr, N);

    // init AFTER csrb (needs dsq); fills ping-pong buffer 0
    k_init_ego<<<(N * 16 + 255) / 256, 256, 0, stream>>>(
        user_emb, item_emb, dsq, egob0, egow0, all_eb, n_user, N);

    for (int k = 0; k < layers; k++) {
        const unsigned short* ebi = (k & 1) ? egob1 : egob0;
        const unsigned short* ewi = (k & 1) ? egow1 : egow0;
        unsigned short* ebo = (k & 1) ? egob0 : egob1;
        unsigned short* ewo = (k & 1) ? egow0 : egow1;
        k_fused<<<nrt, 256, 0, stream>>>(
            row_ptr, csr, dsq, ebi, ewi, ebo, ewo,
            W_gc + (size_t)k * EMB * EMB, b_gc + (size_t)k * EMB,
            W_bi + (size_t)k * EMB * EMB, b_bi + (size_t)k * EMB,
            all_eb, N, (k + 1) * EMB, (k < layers - 1) ? 1 : 0);
    }

    k_gather<<<(3 * batch * 64 + 255) / 256, 256, 0, stream>>>(
        all_eb, users, pos, neg, out, n_user, batch);
}

// Round 10
// 565.544 us; speedup vs baseline: 1.0158x; 1.0158x over previous
//
#include <hip/hip_runtime.h>

#define EMB 64
#define B2SHIFT 8                 // 256 dst rows per bucket
#define B2ROWS 256
#define MAXB 1024                 // LDS hist capacity (586 buckets actual)

typedef short v8s __attribute__((ext_vector_type(8)));
typedef float v4f __attribute__((ext_vector_type(4)));

__device__ __forceinline__ float b2f(unsigned short u) {
    return __uint_as_float(((unsigned int)u) << 16);
}
__device__ __forceinline__ float b2f_lo(unsigned int u) {
    return __uint_as_float(u << 16);
}
__device__ __forceinline__ float b2f_hi(unsigned int u) {
    return __uint_as_float(u & 0xFFFF0000u);
}
__device__ __forceinline__ unsigned short f2b(float f) {
    unsigned int u = __float_as_uint(f);
    u += 0x7FFF + ((u >> 16) & 1);          // round-to-nearest-even
    return (unsigned short)(u >> 16);
}

// ---------------------------------------------------------------------------
// init (x4 vectorized): each thread handles 4 comps (float4 in, 2x dword out)
// egob = bf16(ego); egow = bf16(dsq[n]*ego); all_eb[:,0:64] = bf16(ego) (NT)
// ---------------------------------------------------------------------------
__global__ void k_init_ego(const float* __restrict__ user_emb,
                           const float* __restrict__ item_emb,
                           const float* __restrict__ dsq,
                           unsigned short* __restrict__ egob,
                           unsigned short* __restrict__ egow,
                           unsigned short* __restrict__ all_eb,
                           int n_user, int N) {
    int idx = blockIdx.x * blockDim.x + threadIdx.x;   // over N*16
    int total = N * 16;
    if (idx >= total) return;
    int n = idx >> 4;
    int q = idx & 15;                                  // comps 4q..4q+3
    float4 v = (n < n_user)
        ? ((const float4*)user_emb)[idx]
        : ((const float4*)item_emb)[(size_t)(n - n_user) * 16 + q];
    float dn = dsq[n];
    unsigned int pb0 = (unsigned)f2b(v.x) | ((unsigned)f2b(v.y) << 16);
    unsigned int pb1 = (unsigned)f2b(v.z) | ((unsigned)f2b(v.w) << 16);
    unsigned int pw0 = (unsigned)f2b(dn * v.x) | ((unsigned)f2b(dn * v.y) << 16);
    unsigned int pw1 = (unsigned)f2b(dn * v.z) | ((unsigned)f2b(dn * v.w) << 16);
    unsigned int* egobd = (unsigned int*)egob;
    unsigned int* egowd = (unsigned int*)egow;
    egobd[idx * 2 + 0] = pb0;
    egobd[idx * 2 + 1] = pb1;
    egowd[idx * 2 + 0] = pw0;
    egowd[idx * 2 + 1] = pw1;
    unsigned int* ae = (unsigned int*)all_eb;
    __builtin_nontemporal_store(pb0, &ae[(size_t)n * 128 + q * 2 + 0]);
    __builtin_nontemporal_store(pb1, &ae[(size_t)n * 128 + q * 2 + 1]);
}

// ---------------------------------------------------------------------------
// Bucket histogram (586 buckets): LDS pre-aggregation, ~300K global atomics
// ---------------------------------------------------------------------------
__global__ __launch_bounds__(256) void k_bhist(const int* __restrict__ dst,
                                               int* __restrict__ bins,
                                               int M, int nb2) {
    __shared__ int h[MAXB];
    for (int i = threadIdx.x; i < nb2; i += 256) h[i] = 0;
    __syncthreads();
    for (int e = blockIdx.x * 256 + threadIdx.x; e < M; e += gridDim.x * 256)
        atomicAdd(&h[dst[e] >> B2SHIFT], 1);
    __syncthreads();
    for (int i = threadIdx.x; i < nb2; i += 256)
        if (h[i]) atomicAdd(&bins[i], h[i]);
}

// ---------------------------------------------------------------------------
// Exclusive scan of nb2 (<=1024) bins -> boff[0..P], bcur copy; row_ptr[N]=M
// ---------------------------------------------------------------------------
__global__ __launch_bounds__(1024) void k_bscan(const int* __restrict__ bins,
                                                int* __restrict__ boff,
                                                int* __restrict__ bcur,
                                                int* __restrict__ row_ptr,
                                                int P, int N) {
    __shared__ int buf[1024];
    int tid = threadIdx.x;
    int v = (tid < P) ? bins[tid] : 0;
    buf[tid] = v;
    __syncthreads();
    for (int d = 1; d < 1024; d <<= 1) {
        int add = (tid >= d) ? buf[tid - d] : 0;
        __syncthreads();
        buf[tid] += add;
        __syncthreads();
    }
    if (tid < P) {
        int excl = buf[tid] - v;
        boff[tid] = excl;
        bcur[tid] = excl;
    }
    if (tid == P - 1) {
        boff[P] = buf[tid];
        row_ptr[N] = buf[tid];
    }
}

// ---------------------------------------------------------------------------
// Multisplit pass 1: block-private runs per bucket (single-writer lines)
// entry = (src << 8) | (dst & 255)
// ---------------------------------------------------------------------------
__global__ __launch_bounds__(256) void k_bin(const int* __restrict__ src,
                                             const int* __restrict__ dst,
                                             int* __restrict__ bcur,
                                             int* __restrict__ binned,
                                             int M, int nb2) {
    __shared__ int hist[MAXB];
    __shared__ int runcur[MAXB];
    int chunk = (M + gridDim.x - 1) / gridDim.x;
    int lo = blockIdx.x * chunk;
    int hi = min(lo + chunk, M);
    for (int i = threadIdx.x; i < nb2; i += 256) hist[i] = 0;
    __syncthreads();
    for (int e = lo + threadIdx.x; e < hi; e += 256)
        atomicAdd(&hist[dst[e] >> B2SHIFT], 1);
    __syncthreads();
    for (int i = threadIdx.x; i < nb2; i += 256) {
        int c = hist[i];
        runcur[i] = c ? atomicAdd(&bcur[i], c) : 0;
    }
    __syncthreads();
    for (int e = lo + threadIdx.x; e < hi; e += 256) {
        int d = dst[e];
        int pos = atomicAdd(&runcur[d >> B2SHIFT], 1);
        binned[pos] = (src[e] << B2SHIFT) | (d & (B2ROWS - 1));
    }
}

// ---------------------------------------------------------------------------
// Multisplit pass 2 + CSR finalize (lean): per-bucket LDS histogram -> scan
// -> row_ptr & dsq -> scatter csr inside the bucket's L2-local window
// ---------------------------------------------------------------------------
__global__ __launch_bounds__(256) void k_csrb(const int* __restrict__ boff,
                                              const int* __restrict__ binned,
                                              int* __restrict__ row_ptr,
                                              float* __restrict__ dsq,
                                              int* __restrict__ csr, int N) {
    __shared__ int hist[B2ROWS];
    __shared__ int scan[B2ROWS];
    int b = blockIdx.x;
    int beg = boff[b], end = boff[b + 1];
    int tid = threadIdx.x;
    hist[tid] = 0;
    __syncthreads();
    for (int e = beg + tid; e < end; e += 256)
        atomicAdd(&hist[binned[e] & (B2ROWS - 1)], 1);
    __syncthreads();
    int c = hist[tid];
    scan[tid] = c;
    __syncthreads();
    for (int d = 1; d < B2ROWS; d <<= 1) {
        int add = (tid >= d) ? scan[tid - d] : 0;
        __syncthreads();
        scan[tid] += add;
        __syncthreads();
    }
    int excl = beg + scan[tid] - c;
    int node = (b << B2SHIFT) + tid;
    if (node < N) {
        row_ptr[node] = excl;
        dsq[node] = (c > 0) ? rsqrtf((float)c) : 0.0f;
    }
    __syncthreads();
    hist[tid] = excl;               // reuse as per-node cursor
    __syncthreads();
    for (int e = beg + tid; e < end; e += 256) {
        int v = binned[e];
        int pos = atomicAdd(&hist[v & (B2ROWS - 1)], 1);
        csr[pos] = v >> B2SHIFT;
    }
}

// ---------------------------------------------------------------------------
// side pass v4 (proven best: 78us, VALU 32%, occ 73%): one wave per node,
// lane = component. Indices fetched through the SCALAR pipe: csr[e+k] with
// wave-uniform e compiles to s_load_dwordx4/x8/x16 -> zero readlanes, zero
// vector csr loads, row base stays in SGPRs (SALU addressing + saddr
// gathers). Named scalars only (no arrays -> no PromoteAlloca/LDS pathology).
// ---------------------------------------------------------------------------
__global__ __launch_bounds__(256) void k_side(const int* __restrict__ row_ptr,
                                              const int* __restrict__ csr,
                                              const float* __restrict__ dsq,
                                              const unsigned short* __restrict__ egow,
                                              const unsigned short* __restrict__ egob,
                                              unsigned short* __restrict__ X, int N) {
    int wave = threadIdx.x >> 6;
    int lane = threadIdx.x & 63;
    int n = blockIdx.x * 4 + wave;
    if (n >= N) return;
    int beg = __builtin_amdgcn_readfirstlane(row_ptr[n]);
    int end = __builtin_amdgcn_readfirstlane(row_ptr[n + 1]);
    float a0 = 0.f, a1 = 0.f, a2 = 0.f, a3 = 0.f;
    int e = beg;
    for (; e + 16 <= end; e += 16) {
        int s0  = csr[e + 0],  s1  = csr[e + 1],  s2  = csr[e + 2],  s3  = csr[e + 3];
        int s4  = csr[e + 4],  s5  = csr[e + 5],  s6  = csr[e + 6],  s7  = csr[e + 7];
        int s8  = csr[e + 8],  s9  = csr[e + 9],  s10 = csr[e + 10], s11 = csr[e + 11];
        int s12 = csr[e + 12], s13 = csr[e + 13], s14 = csr[e + 14], s15 = csr[e + 15];
        float v0  = b2f(egow[(size_t)s0  * EMB + lane]);
        float v1  = b2f(egow[(size_t)s1  * EMB + lane]);
        float v2  = b2f(egow[(size_t)s2  * EMB + lane]);
        float v3  = b2f(egow[(size_t)s3  * EMB + lane]);
        float v4  = b2f(egow[(size_t)s4  * EMB + lane]);
        float v5  = b2f(egow[(size_t)s5  * EMB + lane]);
        float v6  = b2f(egow[(size_t)s6  * EMB + lane]);
        float v7  = b2f(egow[(size_t)s7  * EMB + lane]);
        float v8  = b2f(egow[(size_t)s8  * EMB + lane]);
        float v9  = b2f(egow[(size_t)s9  * EMB + lane]);
        float v10 = b2f(egow[(size_t)s10 * EMB + lane]);
        float v11 = b2f(egow[(size_t)s11 * EMB + lane]);
        float v12 = b2f(egow[(size_t)s12 * EMB + lane]);
        float v13 = b2f(egow[(size_t)s13 * EMB + lane]);
        float v14 = b2f(egow[(size_t)s14 * EMB + lane]);
        float v15 = b2f(egow[(size_t)s15 * EMB + lane]);
        a0 += v0;  a1 += v1;  a2 += v2;  a3 += v3;
        a0 += v4;  a1 += v5;  a2 += v6;  a3 += v7;
        a0 += v8;  a1 += v9;  a2 += v10; a3 += v11;
        a0 += v12; a1 += v13; a2 += v14; a3 += v15;
    }
    for (; e + 4 <= end; e += 4) {
        int s0 = csr[e + 0], s1 = csr[e + 1], s2 = csr[e + 2], s3 = csr[e + 3];
        float v0 = b2f(egow[(size_t)s0 * EMB + lane]);
        float v1 = b2f(egow[(size_t)s1 * EMB + lane]);
        float v2 = b2f(egow[(size_t)s2 * EMB + lane]);
        float v3 = b2f(egow[(size_t)s3 * EMB + lane]);
        a0 += v0; a1 += v1; a2 += v2; a3 += v3;
    }
    for (; e < end; ++e) {
        int s0 = csr[e];
        a0 += b2f(egow[(size_t)s0 * EMB + lane]);
    }
    float s = dsq[n] * ((a0 + a1) + (a2 + a3));
    float eg = b2f(egob[(size_t)n * EMB + lane]);
    X[(size_t)n * 128 + lane] = f2b(s);
    X[(size_t)n * 128 + 64 + lane] = f2b(s * eg);
}

// ---------------------------------------------------------------------------
// MFMA transform: C = X @ [Wgc; Wbi] + b  (K=128, bf16 16x16x32)
// W^T staged in LDS as bf16 (stride 136 shorts). 16 B-fragments in regs;
// 4 row-tiles/wave. Epilogue: leaky-relu, quad-shfl row-norm, bf16 stores;
// all_eb stores non-temporal (write-once, read-once at the end).
// ---------------------------------------------------------------------------
__global__ __launch_bounds__(256, 2) void k_mt(
        const unsigned short* __restrict__ X,
        unsigned short* __restrict__ egob, unsigned short* __restrict__ egow,
        const float* __restrict__ dsq,
        const float* __restrict__ Wgc, const float* __restrict__ bgc,
        const float* __restrict__ Wbi, const float* __restrict__ bbi,
        unsigned short* __restrict__ all_eb, int N, int layer_col) {
    __shared__ unsigned short sWT[64 * 136];   // [n][k] bf16, k in [0,128)
    __shared__ float sB[64];
    int tid = threadIdx.x;
    for (int i = tid; i < 64 * 64; i += 256) {
        int k = i >> 6, n = i & 63;
        sWT[n * 136 + k]      = f2b(Wgc[i]);
        sWT[n * 136 + 64 + k] = f2b(Wbi[i]);
    }
    if (tid < 64) sB[tid] = bgc[tid] + bbi[tid];
    __syncthreads();

    int wave = tid >> 6, lane = tid & 63;
    int q = lane >> 4, col = lane & 15;

    v8s Bf[4][4];                               // [nt][kt]
#pragma unroll
    for (int nt = 0; nt < 4; nt++)
#pragma unroll
        for (int kt = 0; kt < 4; kt++)
            Bf[nt][kt] = *(const v8s*)&sWT[(nt * 16 + col) * 136 + kt * 32 + q * 8];

    int nrt = (N + 15) >> 4;
    int rt0 = (blockIdx.x * 4 + wave) * 4;      // 4 row-tiles per wave
    int rt1 = min(rt0 + 4, nrt);
    for (int t = rt0; t < rt1; t++) {
        int r0 = t << 4;
        int rowA = min(r0 + col, N - 1);
        v8s Af[4];
#pragma unroll
        for (int kt = 0; kt < 4; kt++)
            Af[kt] = *(const v8s*)&X[(size_t)rowA * 128 + kt * 32 + q * 8];
        v4f acc[4];
#pragma unroll
        for (int nt = 0; nt < 4; nt++) {
            float b = sB[nt * 16 + col];
            acc[nt] = (v4f){b, b, b, b};
        }
#pragma unroll
        for (int kt = 0; kt < 4; kt++)
#pragma unroll
            for (int nt = 0; nt < 4; nt++)
                acc[nt] = __builtin_amdgcn_mfma_f32_16x16x32_bf16(
                    Af[kt], Bf[nt][kt], acc[nt], 0, 0, 0);
        // epilogue: row = r0 + q*4 + reg, col = nt*16 + (lane&15)
#pragma unroll
        for (int reg = 0; reg < 4; reg++) {
            int row = r0 + q * 4 + reg;
            float v[4];
            float ssq = 0.f;
#pragma unroll
            for (int nt = 0; nt < 4; nt++) {
                float x = acc[nt][reg];
                x = x > 0.f ? x : 0.2f * x;
                v[nt] = x;
                ssq += x * x;
            }
            ssq += __shfl_xor(ssq, 1, 64);
            ssq += __shfl_xor(ssq, 2, 64);
            ssq += __shfl_xor(ssq, 4, 64);
            ssq += __shfl_xor(ssq, 8, 64);
            float inv = 1.0f / fmaxf(sqrtf(ssq), 1e-12f);
            if (row < N) {
                float dn = dsq[row];
#pragma unroll
                for (int nt = 0; nt < 4; nt++) {
                    int c = nt * 16 + col;
                    egob[(size_t)row * EMB + c] = f2b(v[nt]);
                    egow[(size_t)row * EMB + c] = f2b(v[nt] * dn);
                    __builtin_nontemporal_store(
                        f2b(v[nt] * inv),
                        &all_eb[(size_t)row * 256 + layer_col + c]);
                }
            }
        }
    }
}

// ---------------------------------------------------------------------------
// gather (x4 vectorized): thread per 4 comps, 2 dwords in -> float4 out
// out(f32) = [all_eb[users], all_eb[nu+pos], all_eb[nu+neg]]
// ---------------------------------------------------------------------------
__global__ void k_gather(const unsigned short* __restrict__ all_eb,
                         const int* __restrict__ users,
                         const int* __restrict__ pos,
                         const int* __restrict__ neg,
                         float* __restrict__ out, int n_user, int batch) {
    int idx = blockIdx.x * blockDim.x + threadIdx.x;
    int total = batch * 64;
    if (idx >= 3 * total) return;
    int which = idx / total;
    int r = idx - which * total;
    int b = r >> 6;
    int q = r & 63;                       // 4-comp group within the 256-row
    int node;
    if (which == 0) node = users[b];
    else if (which == 1) node = n_user + pos[b];
    else node = n_user + neg[b];
    const unsigned int* ae = (const unsigned int*)all_eb;
    unsigned int d0 = ae[(size_t)node * 128 + q * 2 + 0];
    unsigned int d1 = ae[(size_t)node * 128 + q * 2 + 1];
    float4 o;
    o.x = b2f_lo(d0);
    o.y = b2f_hi(d0);
    o.z = b2f_lo(d1);
    o.w = b2f_hi(d1);
    ((float4*)out)[idx] = o;
}

static inline size_t align256(size_t x) { return (x + 255) & ~(size_t)255; }

extern "C" void kernel_launch(void* const* d_in, const int* in_sizes, int n_in,
                              void* d_out, int out_size, void* d_ws, size_t ws_size,
                              hipStream_t stream) {
    const float* user_emb = (const float*)d_in[0];
    const float* item_emb = (const float*)d_in[1];
    const float* W_gc = (const float*)d_in[2];
    const float* b_gc = (const float*)d_in[3];
    const float* W_bi = (const float*)d_in[4];
    const float* b_bi = (const float*)d_in[5];
    const int* edge_src = (const int*)d_in[7];
    const int* edge_dst = (const int*)d_in[8];
    const int* users = (const int*)d_in[9];
    const int* pos = (const int*)d_in[10];
    const int* neg = (const int*)d_in[11];

    int n_user = in_sizes[0] / EMB;
    int n_item = in_sizes[1] / EMB;
    int N = n_user + n_item;
    int M = in_sizes[6];
    int layers = in_sizes[2] / (EMB * EMB);
    int batch = in_sizes[9];
    float* out = (float*)d_out;

    int nb2 = (N + B2ROWS - 1) >> B2SHIFT;       // 586 buckets
    int nrt = (N + 15) >> 4;                     // 16-row tiles

    // workspace carve (~187 MB)
    char* p = (char*)d_ws;
    unsigned short* egob = (unsigned short*)p;   p += align256((size_t)N * EMB * 2);
    unsigned short* egow = (unsigned short*)p;   p += align256((size_t)N * EMB * 2);
    unsigned short* X = (unsigned short*)p;      p += align256((size_t)N * 128 * 2);
    unsigned short* all_eb = (unsigned short*)p; p += align256((size_t)N * 256 * 2);
    float* dsq = (float*)p;            p += align256((size_t)N * 4);
    int* row_ptr = (int*)p;            p += align256((size_t)(N + 1) * 4);
    int* bins = (int*)p;               p += align256((size_t)nb2 * 4);
    int* boff = (int*)p;               p += align256((size_t)(nb2 + 1) * 4);
    int* bcur = (int*)p;               p += align256((size_t)nb2 * 4);
    int* binned = (int*)p;             p += align256((size_t)M * 4);
    int* csr = (int*)p;                p += align256((size_t)M * 4);

    hipMemsetAsync(bins, 0, (size_t)nb2 * 4, stream);   // 2.3 KB

    // bucket-first CSR build (produces row_ptr, dsq, csr)
    k_bhist<<<512, 256, 0, stream>>>(edge_dst, bins, M, nb2);
    k_bscan<<<1, 1024, 0, stream>>>(bins, boff, bcur, row_ptr, nb2, N);
    k_bin<<<512, 256, 0, stream>>>(edge_src, edge_dst, bcur, binned, M, nb2);
    k_csrb<<<nb2, 256, 0, stream>>>(boff, binned, row_ptr, dsq, csr, N);

    // init AFTER csrb (needs dsq for the pre-scaled gather table)
    k_init_ego<<<(N * 16 + 255) / 256, 256, 0, stream>>>(
        user_emb, item_emb, dsq, egob, egow, all_eb, n_user, N);

    for (int k = 0; k < layers; k++) {
        k_side<<<(N + 3) / 4, 256, 0, stream>>>(row_ptr, csr, dsq, egow, egob, X, N);
        k_mt<<<(nrt + 15) / 16, 256, 0, stream>>>(
            X, egob, egow, dsq,
            W_gc + (size_t)k * EMB * EMB, b_gc + (size_t)k * EMB,
            W_bi + (size_t)k * EMB * EMB, b_bi + (size_t)k * EMB,
            all_eb, N, (k + 1) * EMB);
    }

    k_gather<<<(3 * batch * 64 + 255) / 256, 256, 0, stream>>>(
        all_eb, users, pos, neg, out, n_user, batch);
}